// Round 1
// baseline (161.248 us; speedup 1.0000x reference)
//
#include <hip/hip_runtime.h>
#include <math.h>

#define EPS 1e-12f

// Problem constants (fixed by reference setup_inputs)
#define NN 8
#define TT 2048
#define DD 512
#define KK 64

// ---------------------------------------------------------------------------
// ws layout (in floats):
//   xn    : [N*T*D]   = 8388608   @ 0
//   a     : [N*T*K]   = 1048576   @ 8388608
//   part  : [4*N*K*D] = 1048576   @ 9437184
//   v     : [N*K*D]   =  262144   @ 10485760
//   asum  : [N*K]     =     512   @ 10747904
//   norms : [N*K]     =     512   @ 10748416
//   scale : [N*K]     =     512   @ 10748928
// total 10749440 floats = 41.0 MB
// ---------------------------------------------------------------------------

__global__ __launch_bounds__(256) void k0_zero(float* __restrict__ asum) {
    int i = blockIdx.x * blockDim.x + threadIdx.x;
    if (i < NN * KK) asum[i] = 0.0f;
}

// K1: xn = x / max(||x||_2, eps) along D. One wave per row.
__global__ __launch_bounds__(256) void k1_norm(const float* __restrict__ x,
                                               float* __restrict__ xn) {
    int lane = threadIdx.x & 63;
    int row  = blockIdx.x * 4 + (threadIdx.x >> 6);   // < 16384
    const float4* xr = (const float4*)(x + (size_t)row * DD);
    float4 v0 = xr[lane];
    float4 v1 = xr[lane + 64];
    float ssq = v0.x*v0.x + v0.y*v0.y + v0.z*v0.z + v0.w*v0.w
              + v1.x*v1.x + v1.y*v1.y + v1.z*v1.z + v1.w*v1.w;
#pragma unroll
    for (int m = 32; m >= 1; m >>= 1) ssq += __shfl_xor(ssq, m, 64);
    float s = 1.0f / fmaxf(sqrtf(ssq), EPS);
    v0.x *= s; v0.y *= s; v0.z *= s; v0.w *= s;
    v1.x *= s; v1.y *= s; v1.z *= s; v1.w *= s;
    float4* o = (float4*)(xn + (size_t)row * DD);
    o[lane]      = v0;
    o[lane + 64] = v1;
}

// K2: logits = Xn * W^T + b  (64 rows x 64 clusters per block), softmax over
// clusters (full K=64), write a [N*T, K] and accumulate asum[N,K].
// LDS tiles use an XOR float4-slot swizzle: element (r,c) of a 64x64 tile is
// stored at float4 slot (c>>2) ^ (r>>2) within row r (stride 64 floats).
// Staging writes and both operand b128 reads are then <=2-way bank conflicts.
__global__ __launch_bounds__(256) void k2_assign(const float* __restrict__ xn,
                                                 const float* __restrict__ W,
                                                 const float* __restrict__ b,
                                                 float* __restrict__ a,
                                                 float* __restrict__ asum) {
    __shared__ float4 sX[64 * 16];
    __shared__ float4 sW[64 * 16];
    __shared__ float  sAsum[64];

    const int tid = threadIdx.x;
    const int tx  = tid & 15;        // 0..15 -> cluster groups of 4
    const int ty  = tid >> 4;        // 0..15 -> row groups of 4
    const int row0 = blockIdx.x * 64;  // global (n*T + t) base; tile within one n

    if (tid < 64) sAsum[tid] = 0.0f;

    float acc[4][4] = {};

    for (int dk = 0; dk < 8; ++dk) {  // 8 chunks of 64 over D=512
        const float4* gx = (const float4*)xn + (size_t)row0 * 128 + dk * 16;
        const float4* gw = (const float4*)W + dk * 16;
#pragma unroll
        for (int i = 0; i < 4; ++i) {
            int f4 = tid + i * 256;
            int r = f4 >> 4, q = f4 & 15;
            int slot = r * 16 + ((q ^ (r >> 2)) & 15);
            sX[slot] = gx[(size_t)r * 128 + q];
            sW[slot] = gw[(size_t)r * 128 + q];
        }
        __syncthreads();
#pragma unroll 4
        for (int kb = 0; kb < 16; ++kb) {  // float4 steps over the d-chunk
            float xs[4][4], wsv[4][4];
#pragma unroll
            for (int i = 0; i < 4; ++i) {
                int r = 4 * ty + i;
                float4 t = sX[r * 16 + ((kb ^ (r >> 2)) & 15)];
                xs[i][0] = t.x; xs[i][1] = t.y; xs[i][2] = t.z; xs[i][3] = t.w;
            }
#pragma unroll
            for (int j = 0; j < 4; ++j) {
                int r = 4 * tx + j;
                float4 t = sW[r * 16 + ((kb ^ (r >> 2)) & 15)];
                wsv[j][0] = t.x; wsv[j][1] = t.y; wsv[j][2] = t.z; wsv[j][3] = t.w;
            }
#pragma unroll
            for (int i = 0; i < 4; ++i)
#pragma unroll
                for (int j = 0; j < 4; ++j)
                    acc[i][j] += xs[i][0] * wsv[j][0] + xs[i][1] * wsv[j][1]
                               + xs[i][2] * wsv[j][2] + xs[i][3] * wsv[j][3];
        }
        __syncthreads();
    }

    // bias
    float bj[4];
#pragma unroll
    for (int j = 0; j < 4; ++j) bj[j] = b[4 * tx + j];
#pragma unroll
    for (int i = 0; i < 4; ++i)
#pragma unroll
        for (int j = 0; j < 4; ++j) acc[i][j] += bj[j];

    // softmax over the 64 clusters of each row.  Row r = 4*ty+i lives in the
    // 16 lanes sharing ty (lane bits 0..3 = tx) -> shfl_xor masks 1,2,4,8.
    float av[4][4];
#pragma unroll
    for (int i = 0; i < 4; ++i) {
        float m = fmaxf(fmaxf(acc[i][0], acc[i][1]), fmaxf(acc[i][2], acc[i][3]));
#pragma unroll
        for (int msk = 1; msk <= 8; msk <<= 1) m = fmaxf(m, __shfl_xor(m, msk, 64));
        float s = 0.0f;
#pragma unroll
        for (int j = 0; j < 4; ++j) {
            av[i][j] = expf(acc[i][j] - m);
            s += av[i][j];
        }
#pragma unroll
        for (int msk = 1; msk <= 8; msk <<= 1) s += __shfl_xor(s, msk, 64);
        float inv = 1.0f / s;
#pragma unroll
        for (int j = 0; j < 4; ++j) av[i][j] *= inv;
    }

    // write a[row][k] (coalesced float4)
#pragma unroll
    for (int i = 0; i < 4; ++i) {
        *(float4*)(a + (size_t)(row0 + 4 * ty + i) * KK + 4 * tx) =
            make_float4(av[i][0], av[i][1], av[i][2], av[i][3]);
    }

    // column sums (over the 64 rows of this tile) -> asum[n,k]
    // reduce over ty low bits within wave (lane bits 4,5): masks 16,32
    float cs[4];
#pragma unroll
    for (int j = 0; j < 4; ++j) {
        cs[j] = av[0][j] + av[1][j] + av[2][j] + av[3][j];
#pragma unroll
        for (int msk = 16; msk <= 32; msk <<= 1) cs[j] += __shfl_xor(cs[j], msk, 64);
    }
    __syncthreads();  // sAsum zeroing visible
    if ((ty & 3) == 0) {
#pragma unroll
        for (int j = 0; j < 4; ++j) atomicAdd(&sAsum[4 * tx + j], cs[j]);
    }
    __syncthreads();
    if (tid < 64) {
        int n = row0 >> 11;  // / T
        atomicAdd(&asum[n * KK + tid], sAsum[tid]);
    }
}

// K3: partial[k][d] = sum_{t in chunk} a[n,t,k] * xn[n,t,d]
// block = (n, d-tile of 64, t-chunk of 512); 8*8*4 = 256 blocks.
__global__ __launch_bounds__(256) void k3_vlad(const float* __restrict__ a,
                                               const float* __restrict__ xn,
                                               float* __restrict__ part) {
    __shared__ float4 sA[64 * 16];  // [t][k] tile, swizzled
    __shared__ float4 sX[64 * 16];  // [t][d] tile, swizzled

    const int tid = threadIdx.x;
    const int tx  = tid & 15;   // d groups of 4
    const int ty  = tid >> 4;   // k groups of 4
    const int bid = blockIdx.x;
    const int tc = bid & 3, dt = (bid >> 2) & 7, n = bid >> 5;
    const int trow0 = n * TT + tc * 512;

    float acc[4][4] = {};

    for (int tb = 0; tb < 8; ++tb) {  // 8 stages of 64 t's
        const float4* ga = (const float4*)a + (size_t)(trow0 + tb * 64) * 16;
        const float4* gx = (const float4*)xn + (size_t)(trow0 + tb * 64) * 128 + dt * 16;
#pragma unroll
        for (int i = 0; i < 4; ++i) {
            int f4 = tid + i * 256;
            int r = f4 >> 4, q = f4 & 15;
            int slot = r * 16 + ((q ^ (r >> 2)) & 15);
            sA[slot] = ga[(size_t)r * 16 + q];
            sX[slot] = gx[(size_t)r * 128 + q];
        }
        __syncthreads();
#pragma unroll 8
        for (int t = 0; t < 64; ++t) {
            float4 a4 = sA[t * 16 + ((ty ^ (t >> 2)) & 15)];
            float4 x4 = sX[t * 16 + ((tx ^ (t >> 2)) & 15)];
            float as_[4] = {a4.x, a4.y, a4.z, a4.w};
            float xs_[4] = {x4.x, x4.y, x4.z, x4.w};
#pragma unroll
            for (int i = 0; i < 4; ++i)
#pragma unroll
                for (int j = 0; j < 4; ++j) acc[i][j] += as_[i] * xs_[j];
        }
        __syncthreads();
    }

    // part[tc][n][k][d]: index = (tc*512 + n*64 + k)*512 + dt*64 + d
#pragma unroll
    for (int i = 0; i < 4; ++i) {
        int k = 4 * ty + i;
        *(float4*)(part + ((size_t)tc * 512 + n * 64 + k) * 512 + dt * 64 + 4 * tx) =
            make_float4(acc[i][0], acc[i][1], acc[i][2], acc[i][3]);
    }
}

// K4a: v[n,k,d] = sum_tc part - asum[n,k]*c[k,d]; norms[n,k] = sum_d v^2
__global__ __launch_bounds__(64) void k4a_finish(const float* __restrict__ part,
                                                 const float* __restrict__ asum,
                                                 const float* __restrict__ cent,
                                                 float* __restrict__ v,
                                                 float* __restrict__ norms) {
    int nk = blockIdx.x;             // n*64 + k
    int k  = nk & 63;
    int lane = threadIdx.x;
    float as = asum[nk];
    const float* c = cent + (size_t)k * DD;
    float* vo = v + (size_t)nk * DD;
    float ssq = 0.0f;
#pragma unroll
    for (int j = 0; j < 8; ++j) {
        int d = lane + j * 64;
        float val = part[((size_t)0 * 512 + nk) * 512 + d]
                  + part[((size_t)1 * 512 + nk) * 512 + d]
                  + part[((size_t)2 * 512 + nk) * 512 + d]
                  + part[((size_t)3 * 512 + nk) * 512 + d]
                  - as * c[d];
        vo[d] = val;
        ssq += val * val;
    }
#pragma unroll
    for (int m = 32; m >= 1; m >>= 1) ssq += __shfl_xor(ssq, m, 64);
    if (lane == 0) norms[nk] = ssq;
}

// K4b: per-(n,k) combined scale = 1/(max(||v_nk||,eps) * max(g_n,eps))
__global__ __launch_bounds__(64) void k4b_scale(const float* __restrict__ norms,
                                                float* __restrict__ scale) {
    int n = blockIdx.x, k = threadIdx.x;
    float ssq = norms[n * KK + k];
    float nr = sqrtf(ssq);
    float dn = fmaxf(nr, EPS);
    float t  = nr / dn;      // contribution of normalized row to global norm
    float g2 = t * t;
#pragma unroll
    for (int m = 32; m >= 1; m >>= 1) g2 += __shfl_xor(g2, m, 64);
    float g = sqrtf(g2);
    scale[n * KK + k] = 1.0f / (dn * fmaxf(g, EPS));
}

// K4c: out = v * scale[n,k]
__global__ __launch_bounds__(256) void k4c_out(const float* __restrict__ v,
                                               const float* __restrict__ scale,
                                               float* __restrict__ out) {
    int idx4 = blockIdx.x * 256 + threadIdx.x;  // < 65536 float4s
    int nk = idx4 >> 7;                          // 128 float4 per (n,k)
    float s = scale[nk];
    float4 val = ((const float4*)v)[idx4];
    val.x *= s; val.y *= s; val.z *= s; val.w *= s;
    ((float4*)out)[idx4] = val;
}

extern "C" void kernel_launch(void* const* d_in, const int* in_sizes, int n_in,
                              void* d_out, int out_size, void* d_ws, size_t ws_size,
                              hipStream_t stream) {
    const float* x    = (const float*)d_in[0];
    const float* W    = (const float*)d_in[1];
    const float* b    = (const float*)d_in[2];
    const float* cent = (const float*)d_in[3];
    float* out = (float*)d_out;

    float* w     = (float*)d_ws;
    float* xn    = w;
    float* a     = w + 8388608;
    float* part  = w + 9437184;
    float* v     = w + 10485760;
    float* asum  = w + 10747904;
    float* norms = w + 10748416;
    float* scale = w + 10748928;

    hipLaunchKernelGGL(k0_zero,    dim3(2),    dim3(256), 0, stream, asum);
    hipLaunchKernelGGL(k1_norm,    dim3(4096), dim3(256), 0, stream, x, xn);
    hipLaunchKernelGGL(k2_assign,  dim3(256),  dim3(256), 0, stream, xn, W, b, a, asum);
    hipLaunchKernelGGL(k3_vlad,    dim3(256),  dim3(256), 0, stream, a, xn, part);
    hipLaunchKernelGGL(k4a_finish, dim3(512),  dim3(64),  0, stream, part, asum, cent, v, norms);
    hipLaunchKernelGGL(k4b_scale,  dim3(8),    dim3(64),  0, stream, norms, scale);
    hipLaunchKernelGGL(k4c_out,    dim3(256),  dim3(256), 0, stream, v, scale, out);
}

// Round 2
// 127.598 us; speedup vs baseline: 1.2637x; 1.2637x over previous
//
#include <hip/hip_runtime.h>
#include <math.h>

#define EPS 1e-12f
#define NN 8
#define TT 2048
#define DD 512
#define KK 64

typedef short short8 __attribute__((ext_vector_type(8)));
typedef float floatx4 __attribute__((ext_vector_type(4)));

// fp32 -> bf16 round-to-nearest-even
__device__ __forceinline__ unsigned short f2bf(float f) {
    unsigned int u = __float_as_uint(f);
    u += 0x7FFFu + ((u >> 16) & 1u);
    return (unsigned short)(u >> 16);
}
__device__ __forceinline__ unsigned int pack2(float a, float b) {
    return (unsigned int)f2bf(a) | ((unsigned int)f2bf(b) << 16);
}

// ---------------------------------------------------------------------------
// ws layout (float units):
//   xn   bf16 [N*T][D]      @ 0         (4194304 floats of space)
//   xnT  bf16 [N][D][T]     @ 4194304   (4194304)
//   aT   bf16 [N][K][T]     @ 8388608   (524288)
//   Wb   bf16 [K][D]        @ 8912896   (16384)
//   part f32  [4][N*K][D]   @ 8929280   (1048576)
//   v    f32  [N*K][D]      @ 9977856   (262144)
//   asum f32  [N*K]         @ 10240000
//   norms f32 [N*K]         @ 10240512
//   scale f32 [N*K]         @ 10241024
// total 10241536 floats = 40.97 MB
// ---------------------------------------------------------------------------

// K0: convert W to bf16, zero asum
__global__ __launch_bounds__(256) void k0_prep(const float* __restrict__ W,
                                               unsigned short* __restrict__ Wb,
                                               float* __restrict__ asum) {
    int i = blockIdx.x * 256 + threadIdx.x;  // < 32768
    Wb[i] = f2bf(W[i]);
    if (i < NN * KK) asum[i] = 0.0f;
}

// K1: per-row L2 normalize; write xn (bf16, [t][d]) and xnT (bf16, [n][d][t])
// block = 32 rows, 8 threads/row x 64 floats. LDS 32x520 ushort for transpose.
__global__ __launch_bounds__(256) void k1_norm(const float* __restrict__ x,
                                               unsigned short* __restrict__ xn,
                                               unsigned short* __restrict__ xnT) {
    __shared__ unsigned short lds[32 * 520];
    const int tid = threadIdx.x;
    const int r = tid >> 3, q = tid & 7;
    const int t0 = blockIdx.x * 32;       // global row base
    const int n = t0 >> 11;
    const int tloc = t0 & (TT - 1);

    const float4* xr = (const float4*)(x + (size_t)(t0 + r) * DD) + q * 16;
    float4 vb[16];
    float ssq = 0.0f;
#pragma unroll
    for (int i = 0; i < 16; ++i) {
        vb[i] = xr[i];
        ssq += vb[i].x * vb[i].x + vb[i].y * vb[i].y
             + vb[i].z * vb[i].z + vb[i].w * vb[i].w;
    }
#pragma unroll
    for (int m = 1; m <= 4; m <<= 1) ssq += __shfl_xor(ssq, m, 64);
    float s = 1.0f / fmaxf(sqrtf(ssq), EPS);

    unsigned short* xno = xn + (size_t)(t0 + r) * DD + q * 64;
    unsigned short* ldp = lds + r * 520 + q * 64;
#pragma unroll
    for (int j = 0; j < 8; ++j) {
        float4 a = vb[2 * j], b = vb[2 * j + 1];
        uint4 pk;
        pk.x = pack2(a.x * s, a.y * s);
        pk.y = pack2(a.z * s, a.w * s);
        pk.z = pack2(b.x * s, b.y * s);
        pk.w = pack2(b.z * s, b.w * s);
        *(uint4*)(xno + j * 8) = pk;
        *(uint4*)(ldp + j * 8) = pk;
    }
    __syncthreads();

    // transpose out: each thread handles 2 d-columns, 32 t each
#pragma unroll
    for (int c = 0; c < 2; ++c) {
        int d = tid + c * 256;
        unsigned short col[32];
#pragma unroll
        for (int rr = 0; rr < 32; ++rr) col[rr] = lds[rr * 520 + d];
        uint4* o = (uint4*)(xnT + ((size_t)(n * DD + d)) * TT + tloc);
#pragma unroll
        for (int j = 0; j < 4; ++j) {
            uint4 pk;
            pk.x = (unsigned int)col[8 * j + 0] | ((unsigned int)col[8 * j + 1] << 16);
            pk.y = (unsigned int)col[8 * j + 2] | ((unsigned int)col[8 * j + 3] << 16);
            pk.z = (unsigned int)col[8 * j + 4] | ((unsigned int)col[8 * j + 5] << 16);
            pk.w = (unsigned int)col[8 * j + 6] | ((unsigned int)col[8 * j + 7] << 16);
            o[j] = pk;
        }
    }
}

// K2: logits = Xn*W^T + b via MFMA; softmax over K=64 in registers;
// write aT[n][k][t] bf16 and asum[n][k] (atomic).
// Per wave: 16 t-rows x 64 clusters. A-frag: xn[t][d] b128; B-frag: Wb[k][d] b128.
__global__ __launch_bounds__(256) void k2_assign(const unsigned short* __restrict__ xn,
                                                 const unsigned short* __restrict__ Wb,
                                                 const float* __restrict__ b,
                                                 unsigned short* __restrict__ aT,
                                                 float* __restrict__ asum) {
    const int tid = threadIdx.x;
    const int wave = tid >> 6, lane = tid & 63;
    const int l = lane & 15, q = lane >> 4;
    const int row0 = blockIdx.x * 64 + wave * 16;  // global t
    const int n = row0 >> 11;
    const int tloc = row0 & (TT - 1);

    const unsigned short* arow = xn + (size_t)(row0 + l) * DD + q * 8;
    const unsigned short* w0 = Wb + (size_t)(0 * 16 + l) * DD + q * 8;
    const unsigned short* w1 = Wb + (size_t)(1 * 16 + l) * DD + q * 8;
    const unsigned short* w2 = Wb + (size_t)(2 * 16 + l) * DD + q * 8;
    const unsigned short* w3 = Wb + (size_t)(3 * 16 + l) * DD + q * 8;

    floatx4 acc0 = {0.f, 0.f, 0.f, 0.f}, acc1 = acc0, acc2 = acc0, acc3 = acc0;
#pragma unroll
    for (int s = 0; s < 16; ++s) {
        short8 af = *(const short8*)(arow + s * 32);
        acc0 = __builtin_amdgcn_mfma_f32_16x16x32_bf16(af, *(const short8*)(w0 + s * 32), acc0, 0, 0, 0);
        acc1 = __builtin_amdgcn_mfma_f32_16x16x32_bf16(af, *(const short8*)(w1 + s * 32), acc1, 0, 0, 0);
        acc2 = __builtin_amdgcn_mfma_f32_16x16x32_bf16(af, *(const short8*)(w2 + s * 32), acc2, 0, 0, 0);
        acc3 = __builtin_amdgcn_mfma_f32_16x16x32_bf16(af, *(const short8*)(w3 + s * 32), acc3, 0, 0, 0);
    }

    // bias per cluster (col = h*16 + l)
    float bj0 = b[0 * 16 + l], bj1 = b[1 * 16 + l], bj2 = b[2 * 16 + l], bj3 = b[3 * 16 + l];
    float av[4][4];  // [h][r]
#pragma unroll
    for (int r = 0; r < 4; ++r) {
        float v0 = acc0[r] + bj0, v1 = acc1[r] + bj1, v2 = acc2[r] + bj2, v3 = acc3[r] + bj3;
        float m = fmaxf(fmaxf(v0, v1), fmaxf(v2, v3));
#pragma unroll
        for (int msk = 1; msk <= 8; msk <<= 1) m = fmaxf(m, __shfl_xor(m, msk, 64));
        float e0 = __expf(v0 - m), e1 = __expf(v1 - m), e2 = __expf(v2 - m), e3 = __expf(v3 - m);
        float ssum = e0 + e1 + e2 + e3;
#pragma unroll
        for (int msk = 1; msk <= 8; msk <<= 1) ssum += __shfl_xor(ssum, msk, 64);
        float inv = 1.0f / ssum;
        av[0][r] = e0 * inv; av[1][r] = e1 * inv; av[2][r] = e2 * inv; av[3][r] = e3 * inv;
    }

    // aT[n][k][t]: per (h): 4 consecutive t (r=0..3) at k = h*16+l, t = tloc+4q+r
#pragma unroll
    for (int h = 0; h < 4; ++h) {
        uint2 p;
        p.x = pack2(av[h][0], av[h][1]);
        p.y = pack2(av[h][2], av[h][3]);
        *(uint2*)(aT + ((size_t)(n * KK + h * 16 + l)) * TT + tloc + q * 4) = p;
    }

    // asum: sum over this wave's 16 t, reduce across quads, atomic from quad 0
#pragma unroll
    for (int h = 0; h < 4; ++h) {
        float sh = av[h][0] + av[h][1] + av[h][2] + av[h][3];
        sh += __shfl_xor(sh, 16, 64);
        sh += __shfl_xor(sh, 32, 64);
        if (q == 0) atomicAdd(&asum[n * KK + h * 16 + l], sh);
    }
}

// K3: part[tc][n*64+k][d] = sum_{t in chunk} a[n,t,k]*xn[n,t,d] via MFMA.
// A-frag: aT[k][t] b128; B-frag: xnT[d][t] b128. block=(tc,dt,n), 4 waves x 16k.
__global__ __launch_bounds__(256) void k3_vlad(const unsigned short* __restrict__ aT,
                                               const unsigned short* __restrict__ xnT,
                                               float* __restrict__ part) {
    const int tid = threadIdx.x;
    const int wave = tid >> 6, lane = tid & 63;
    const int l = lane & 15, q = lane >> 4;
    const int bid = blockIdx.x;
    const int tc = bid & 3, dt = (bid >> 2) & 7, n = bid >> 5;
    const int k0w = wave * 16;

    const unsigned short* arow = aT + ((size_t)(n * KK + k0w + l)) * TT + tc * 512 + q * 8;
    const unsigned short* b0 = xnT + ((size_t)(n * DD + dt * 64 + 0 * 16 + l)) * TT + tc * 512 + q * 8;
    const unsigned short* b1 = xnT + ((size_t)(n * DD + dt * 64 + 1 * 16 + l)) * TT + tc * 512 + q * 8;
    const unsigned short* b2 = xnT + ((size_t)(n * DD + dt * 64 + 2 * 16 + l)) * TT + tc * 512 + q * 8;
    const unsigned short* b3 = xnT + ((size_t)(n * DD + dt * 64 + 3 * 16 + l)) * TT + tc * 512 + q * 8;

    floatx4 acc0 = {0.f, 0.f, 0.f, 0.f}, acc1 = acc0, acc2 = acc0, acc3 = acc0;
#pragma unroll
    for (int s = 0; s < 16; ++s) {
        short8 af = *(const short8*)(arow + s * 32);
        acc0 = __builtin_amdgcn_mfma_f32_16x16x32_bf16(af, *(const short8*)(b0 + s * 32), acc0, 0, 0, 0);
        acc1 = __builtin_amdgcn_mfma_f32_16x16x32_bf16(af, *(const short8*)(b1 + s * 32), acc1, 0, 0, 0);
        acc2 = __builtin_amdgcn_mfma_f32_16x16x32_bf16(af, *(const short8*)(b2 + s * 32), acc2, 0, 0, 0);
        acc3 = __builtin_amdgcn_mfma_f32_16x16x32_bf16(af, *(const short8*)(b3 + s * 32), acc3, 0, 0, 0);
    }

    // C: row k = k0w + 4q + r, col d = dt*64 + h*16 + l
    float* po = part + ((size_t)(tc * 512 + n * KK + k0w + 4 * q)) * DD + dt * 64 + l;
#pragma unroll
    for (int r = 0; r < 4; ++r) {
        po[(size_t)r * DD + 0 * 16] = acc0[r];
        po[(size_t)r * DD + 1 * 16] = acc1[r];
        po[(size_t)r * DD + 2 * 16] = acc2[r];
        po[(size_t)r * DD + 3 * 16] = acc3[r];
    }
}

// K4a: v = sum_tc part - asum*c; norms = ||v||^2 per (n,k)
__global__ __launch_bounds__(64) void k4a_finish(const float* __restrict__ part,
                                                 const float* __restrict__ asum,
                                                 const float* __restrict__ cent,
                                                 float* __restrict__ v,
                                                 float* __restrict__ norms) {
    int nk = blockIdx.x;
    int k = nk & 63;
    int lane = threadIdx.x;
    float as = asum[nk];
    const float* c = cent + (size_t)k * DD;
    float* vo = v + (size_t)nk * DD;
    float ssq = 0.0f;
#pragma unroll
    for (int j = 0; j < 8; ++j) {
        int d = lane + j * 64;
        float val = part[((size_t)0 * 512 + nk) * DD + d]
                  + part[((size_t)1 * 512 + nk) * DD + d]
                  + part[((size_t)2 * 512 + nk) * DD + d]
                  + part[((size_t)3 * 512 + nk) * DD + d]
                  - as * c[d];
        vo[d] = val;
        ssq += val * val;
    }
#pragma unroll
    for (int m = 32; m >= 1; m >>= 1) ssq += __shfl_xor(ssq, m, 64);
    if (lane == 0) norms[nk] = ssq;
}

// K4b: scale[n,k] = 1/(max(||v_nk||,eps) * max(g_n,eps))
__global__ __launch_bounds__(64) void k4b_scale(const float* __restrict__ norms,
                                                float* __restrict__ scale) {
    int n = blockIdx.x, k = threadIdx.x;
    float ssq = norms[n * KK + k];
    float nr = sqrtf(ssq);
    float dn = fmaxf(nr, EPS);
    float t = nr / dn;
    float g2 = t * t;
#pragma unroll
    for (int m = 32; m >= 1; m >>= 1) g2 += __shfl_xor(g2, m, 64);
    float g = sqrtf(g2);
    scale[n * KK + k] = 1.0f / (dn * fmaxf(g, EPS));
}

// K4c: out = v * scale[n,k]
__global__ __launch_bounds__(256) void k4c_out(const float* __restrict__ v,
                                               const float* __restrict__ scale,
                                               float* __restrict__ out) {
    int idx4 = blockIdx.x * 256 + threadIdx.x;
    int nk = idx4 >> 7;
    float s = scale[nk];
    float4 val = ((const float4*)v)[idx4];
    val.x *= s; val.y *= s; val.z *= s; val.w *= s;
    ((float4*)out)[idx4] = val;
}

extern "C" void kernel_launch(void* const* d_in, const int* in_sizes, int n_in,
                              void* d_out, int out_size, void* d_ws, size_t ws_size,
                              hipStream_t stream) {
    const float* x    = (const float*)d_in[0];
    const float* W    = (const float*)d_in[1];
    const float* b    = (const float*)d_in[2];
    const float* cent = (const float*)d_in[3];
    float* out = (float*)d_out;

    float* w = (float*)d_ws;
    unsigned short* xn  = (unsigned short*)(w + 0);
    unsigned short* xnT = (unsigned short*)(w + 4194304);
    unsigned short* aT  = (unsigned short*)(w + 8388608);
    unsigned short* Wb  = (unsigned short*)(w + 8912896);
    float* part  = w + 8929280;
    float* v     = w + 9977856;
    float* asum  = w + 10240000;
    float* norms = w + 10240512;
    float* scale = w + 10241024;

    hipLaunchKernelGGL(k0_prep,    dim3(128), dim3(256), 0, stream, W, Wb, asum);
    hipLaunchKernelGGL(k1_norm,    dim3(512), dim3(256), 0, stream, x, xn, xnT);
    hipLaunchKernelGGL(k2_assign,  dim3(256), dim3(256), 0, stream, xn, Wb, b, aT, asum);
    hipLaunchKernelGGL(k3_vlad,    dim3(256), dim3(256), 0, stream, aT, xnT, part);
    hipLaunchKernelGGL(k4a_finish, dim3(512), dim3(64),  0, stream, part, asum, cent, v, norms);
    hipLaunchKernelGGL(k4b_scale,  dim3(8),   dim3(64),  0, stream, norms, scale);
    hipLaunchKernelGGL(k4c_out,    dim3(256), dim3(256), 0, stream, v, scale, out);
}